// Round 3
// baseline (134.479 us; speedup 1.0000x reference)
//
#include <hip/hip_runtime.h>
#include <hip/hip_bf16.h>

// CondConv: B=32, CIN=128, COUT=256, K=3, E=8, H=W=64 -> out [32,256,62,62] fp32
// Pipeline: nhwc(+pool partials) -> reduce -> routing -> combine(bf16 cw) ->
//           implicit-GEMM MFMA conv (256x256 tile, dbuf LDS, counted vmcnt,
//           m201-style 4-phase quadrant schedule + setprio).

#define CC_B    32
#define CC_CIN  128
#define CC_COUT 256
#define CC_NP   3844   // 62*62
#define CC_NT   18     // K-tiles: 9 taps x 2 cin-halves of 64

typedef __attribute__((ext_vector_type(8))) short bf16x8;
typedef __attribute__((ext_vector_type(4))) float f32x4;

// ------------------------------------------------- NHWC cast + pool partials
__global__ void cc_nhwc(const float* __restrict__ x, __hip_bfloat16* __restrict__ xn,
                        float* __restrict__ psum) {
    const int b = blockIdx.x >> 6, y = blockIdx.x & 63;   // 2048 blocks
    __shared__ float lds[64 * 129];                        // [x][cin], +1 pad
    __shared__ float sred[256];
    const int t = threadIdx.x;                             // 256
    const float* src = x + (size_t)b * CC_CIN * 4096 + y * 64;
#pragma unroll
    for (int i = 0; i < 32; ++i) {
        const int idx = i * 256 + t;
        const int cin = idx >> 6, xx = idx & 63;
        lds[xx * 129 + cin] = src[(size_t)cin * 4096 + xx];
    }
    __syncthreads();
    __hip_bfloat16* dst = xn + ((size_t)b * 4096 + y * 64) * CC_CIN;
#pragma unroll
    for (int j = 0; j < 4; ++j) {
        const int cidx = j * 256 + t;                      // 1024 chunks of 8 cin
        const int xx = cidx >> 4, c8 = (cidx & 15) * 8;
        union { __hip_bfloat16 h[8]; uint4 v; } u;
#pragma unroll
        for (int jj = 0; jj < 8; ++jj) u.h[jj] = __float2bfloat16(lds[xx * 129 + c8 + jj]);
        *reinterpret_cast<uint4*>(dst + (size_t)xx * CC_CIN + c8) = u.v;
    }
    // pool partial: sum over the 64 x's of this row
    const int cin = t & 127, xh = (t >> 7) * 32;
    float s = 0.f;
#pragma unroll
    for (int xx = 0; xx < 32; ++xx) s += lds[(xh + xx) * 129 + cin];
    sred[t] = s;
    __syncthreads();
    if (t < 128) psum[((size_t)b * 64 + y) * CC_CIN + t] = sred[t] + sred[t + 128];
}

// ----------------------------------------------------------------- reduce --
__global__ void cc_reduce(const float* __restrict__ psum, float* __restrict__ pooled) {
    const int b = blockIdx.x, c = threadIdx.x;             // 32 blocks x 128
    const float* p = psum + (size_t)b * 64 * CC_CIN + c;
    float s = 0.f;
#pragma unroll 8
    for (int y = 0; y < 64; ++y) s += p[(size_t)y * CC_CIN];
    pooled[b * CC_CIN + c] = s * (1.f / 4096.f);
}

// -------------------------------------------------------------- routing -----
__global__ void cc_routing(const float* __restrict__ pooled,
                           const float* __restrict__ rw_w,
                           const float* __restrict__ rw_b,
                           float* __restrict__ rweights) {
    const int t = threadIdx.x;                 // 256 = 32 b x 8 e
    const int b = t >> 3, e = t & 7;
    const float* p = pooled + b * CC_CIN;
    const float* w = rw_w + e * CC_CIN;
    float acc = rw_b[e];
#pragma unroll 8
    for (int i = 0; i < CC_CIN; ++i) acc += p[i] * w[i];
    float m = acc;
#pragma unroll
    for (int off = 1; off < 8; off <<= 1) m = fmaxf(m, __shfl_xor(m, off, 64));
    const float ex = __expf(acc - m);
    float sum = ex;
#pragma unroll
    for (int off = 1; off < 8; off <<= 1) sum += __shfl_xor(sum, off, 64);
    rweights[t] = ex / sum;
}

// -------------------------------------------------------------- combine -----
// cw[b][t9][cout][cin] (bf16) = sum_e rw[b][e] * EW[e][cout][cin][ky][kx]
__global__ void cc_combine(const float* __restrict__ ew,
                           const float* __restrict__ rw,
                           __hip_bfloat16* __restrict__ cw) {
    const int t9 = blockIdx.x >> 8;            // 0..8
    const int cout = blockIdx.x & 255;
    const int cin = threadIdx.x;               // 128 threads
    __shared__ float rws[256];
    rws[cin] = rw[cin];
    rws[cin + 128] = rw[cin + 128];
    __syncthreads();
    float wv[8];
    const size_t base = ((size_t)cout * CC_CIN + cin) * 9 + t9;
#pragma unroll
    for (int e = 0; e < 8; ++e) wv[e] = ew[base + (size_t)e * (CC_COUT * CC_CIN * 9)];
#pragma unroll 4
    for (int b = 0; b < CC_B; ++b) {
        float acc = 0.f;
#pragma unroll
        for (int e = 0; e < 8; ++e) acc += rws[b * 8 + e] * wv[e];
        cw[(((size_t)b * 9 + t9) * CC_COUT + cout) * CC_CIN + cin] = __float2bfloat16(acc);
    }
}

// ----------------------------------------------------------------- conv -----
__device__ __forceinline__ void gload_lds16(const void* g, void* l) {
    __builtin_amdgcn_global_load_lds(
        (const __attribute__((address_space(1))) unsigned int*)g,
        (__attribute__((address_space(3))) unsigned int*)l, 16, 0, 0);
}

// grid (16, 32), block 512 (8 waves, 2M x 4N). Tile BM=256 couts x BN=256 pos,
// BK=64. LDS 128KB: A dbuf 2x32KB @0, B dbuf 2x32KB @64KB. K-tile t in buf[t&1].
// 4-phase quadrant schedule per K-tile (m201 port):
//   open: vmcnt(8) [stage(t) retired; stage(t+1) in flight] + barrier
//   ph0: ds A-half0 + B-half0 | bar | lgkm0 | prio1 MFMA(m0..3,n0..1) prio0 | bar
//   ph1: ds B-half1           | bar | lgkm0 | prio1 MFMA(m0..3,n2..3) prio0 | bar
//   ph2: ds A-half1, stage B(t+2) | bar | lgkm0 | prio1 MFMA(m4..7,n0..1) prio0 | bar
//   ph3: stage A(t+2), prio1 MFMA(m4..7,n2..3) prio0   (register-only)
// Race safety: B reads drained (per-wave lgkm0) before ph1-close barrier ->
// stage-B in ph2 safe; A reads drained before ph2-close -> stage-A in ph3 safe.
// Swizzle: slot s of 128B row r holds source chunk s^(r&7) (linear LDS dest,
// pre-swizzled per-lane global source).
__global__ __launch_bounds__(512, 2) void cc_conv(
    const __hip_bfloat16* __restrict__ xn,   // [B][64][64][128]
    const __hip_bfloat16* __restrict__ cw,   // [B][9][256][128]
    float* __restrict__ out)                 // [B][256][3844]
{
    __shared__ __align__(16) char smem[131072];
    const int n0 = blockIdx.x * 256;
    const int b  = blockIdx.y;
    const int tid = threadIdx.x;
    const int wid = tid >> 6, lane = tid & 63;
    const int waveM = wid >> 2, waveN = wid & 3;

    f32x4 acc[8][4];
#pragma unroll
    for (int i = 0; i < 8; ++i)
#pragma unroll
        for (int j = 0; j < 4; ++j) acc[i][j] = (f32x4){0.f, 0.f, 0.f, 0.f};

    // staging: wave w, issue i covers rows w*32+i*8..+7; lane -> row l>>3,
    // slot l&7; source chunk pre-swizzled: slot s of row r gets chunk s^(r&7)
    const int gsw = (lane & 7) ^ (lane >> 3);
    int laOff[4], lbOff[4];
#pragma unroll
    for (int i = 0; i < 4; ++i) {
        const int row = wid * 32 + i * 8 + (lane >> 3);
        laOff[i] = row * CC_CIN + gsw * 8;
        int p = n0 + row; if (p > CC_NP - 1) p = CC_NP - 1;   // tail clamp
        const int oy = p / 62, ox = p - oy * 62;
        lbOff[i] = (oy * 64 + ox) * CC_CIN + gsw * 8;
    }

    const __hip_bfloat16* cwb = cw + (size_t)b * 9 * CC_COUT * CC_CIN;
    const __hip_bfloat16* xnb = xn + (size_t)b * 4096 * CC_CIN;

    auto stageA = [&](int t) {
        const int t9 = t >> 1;
        const int aoff = t9 * (CC_COUT * CC_CIN) + (t & 1) * 64;
        char* Ab = smem + (t & 1) * 32768 + wid * 4096;
#pragma unroll
        for (int i = 0; i < 4; ++i)
            gload_lds16(cwb + aoff + laOff[i], Ab + i * 1024);
    };
    auto stageB = [&](int t) {
        const int t9 = t >> 1;
        const int ky = (t9 * 11) >> 5;          // t9/3 for t9<9
        const int kx = t9 - ky * 3;
        const int boff = (ky * 64 + kx) * CC_CIN + (t & 1) * 64;
        char* Bb = smem + 65536 + (t & 1) * 32768 + wid * 4096;
#pragma unroll
        for (int i = 0; i < 4; ++i)
            gload_lds16(xnb + boff + lbOff[i], Bb + i * 1024);
    };

    const int rl = lane & 15, q = lane >> 4, l7 = lane & 7;

    // prologue: 2 K-tiles in flight (16 loads)
    stageA(0); stageB(0);
    stageA(1); stageB(1);

#pragma unroll 1
    for (int t = 0; t < CC_NT; ++t) {
        const char* Ab = smem + (t & 1) * 32768;
        const char* Bb = smem + 65536 + (t & 1) * 32768;

        // ---- tile open: stage(t) globally visible
        if (t < CC_NT - 1) asm volatile("s_waitcnt vmcnt(8)" ::: "memory");
        else               asm volatile("s_waitcnt vmcnt(0)" ::: "memory");
        asm volatile("s_barrier" ::: "memory");

        bf16x8 af[8], bf0[4], bf1[4];

        // ---- ph0: A-half0 (mf 0..3) + B-half0 (nf 0..1)
#pragma unroll
        for (int mf = 0; mf < 4; ++mf)
#pragma unroll
            for (int kk = 0; kk < 2; ++kk) {
                const int r = waveM * 128 + mf * 16 + rl;
                af[mf * 2 + kk] = *(const bf16x8*)(Ab + r * 128 + (((kk * 4 + q) ^ l7) * 16));
            }
#pragma unroll
        for (int nf = 0; nf < 2; ++nf)
#pragma unroll
            for (int kk = 0; kk < 2; ++kk) {
                const int r = waveN * 64 + nf * 16 + rl;
                bf0[nf * 2 + kk] = *(const bf16x8*)(Bb + r * 128 + (((kk * 4 + q) ^ l7) * 16));
            }
        asm volatile("s_barrier" ::: "memory");
        asm volatile("s_waitcnt lgkmcnt(0)" ::: "memory");
        __builtin_amdgcn_s_setprio(1);
#pragma unroll
        for (int mf = 0; mf < 4; ++mf)
#pragma unroll
            for (int nf = 0; nf < 2; ++nf)
#pragma unroll
                for (int kk = 0; kk < 2; ++kk)
                    acc[mf][nf] = __builtin_amdgcn_mfma_f32_16x16x32_bf16(
                        af[mf * 2 + kk], bf0[nf * 2 + kk], acc[mf][nf], 0, 0, 0);
        __builtin_amdgcn_s_setprio(0);
        asm volatile("s_barrier" ::: "memory");

        // ---- ph1: B-half1 (nf 2..3)
#pragma unroll
        for (int nf = 0; nf < 2; ++nf)
#pragma unroll
            for (int kk = 0; kk < 2; ++kk) {
                const int r = waveN * 64 + (nf + 2) * 16 + rl;
                bf1[nf * 2 + kk] = *(const bf16x8*)(Bb + r * 128 + (((kk * 4 + q) ^ l7) * 16));
            }
        asm volatile("s_barrier" ::: "memory");
        asm volatile("s_waitcnt lgkmcnt(0)" ::: "memory");
        __builtin_amdgcn_s_setprio(1);
#pragma unroll
        for (int mf = 0; mf < 4; ++mf)
#pragma unroll
            for (int nf = 0; nf < 2; ++nf)
#pragma unroll
                for (int kk = 0; kk < 2; ++kk)
                    acc[mf][nf + 2] = __builtin_amdgcn_mfma_f32_16x16x32_bf16(
                        af[mf * 2 + kk], bf1[nf * 2 + kk], acc[mf][nf + 2], 0, 0, 0);
        __builtin_amdgcn_s_setprio(0);
        asm volatile("s_barrier" ::: "memory");

        // ---- ph2: A-half1 (mf 4..7, reuses af regs) + stage B(t+2)
#pragma unroll
        for (int mf = 0; mf < 4; ++mf)
#pragma unroll
            for (int kk = 0; kk < 2; ++kk) {
                const int r = waveM * 128 + (mf + 4) * 16 + rl;
                af[mf * 2 + kk] = *(const bf16x8*)(Ab + r * 128 + (((kk * 4 + q) ^ l7) * 16));
            }
        if (t + 2 < CC_NT) stageB(t + 2);
        asm volatile("s_barrier" ::: "memory");
        asm volatile("s_waitcnt lgkmcnt(0)" ::: "memory");
        __builtin_amdgcn_s_setprio(1);
#pragma unroll
        for (int mf = 0; mf < 4; ++mf)
#pragma unroll
            for (int nf = 0; nf < 2; ++nf)
#pragma unroll
                for (int kk = 0; kk < 2; ++kk)
                    acc[mf + 4][nf] = __builtin_amdgcn_mfma_f32_16x16x32_bf16(
                        af[mf * 2 + kk], bf0[nf * 2 + kk], acc[mf + 4][nf], 0, 0, 0);
        __builtin_amdgcn_s_setprio(0);
        asm volatile("s_barrier" ::: "memory");

        // ---- ph3: stage A(t+2) + register-only MFMA quadrant
        if (t + 2 < CC_NT) stageA(t + 2);
        __builtin_amdgcn_s_setprio(1);
#pragma unroll
        for (int mf = 0; mf < 4; ++mf)
#pragma unroll
            for (int nf = 0; nf < 2; ++nf)
#pragma unroll
                for (int kk = 0; kk < 2; ++kk)
                    acc[mf + 4][nf + 2] = __builtin_amdgcn_mfma_f32_16x16x32_bf16(
                        af[mf * 2 + kk], bf1[nf * 2 + kk], acc[mf + 4][nf + 2], 0, 0, 0);
        __builtin_amdgcn_s_setprio(0);
    }

    // epilogue: C/D map col=lane&15 (p), row=(lane>>4)*4+j (cout)
    const int q4 = (lane >> 4) * 4;
#pragma unroll
    for (int mf = 0; mf < 8; ++mf) {
        const int crow = waveM * 128 + mf * 16 + q4;
#pragma unroll
        for (int nf = 0; nf < 4; ++nf) {
            const int p = n0 + waveN * 64 + nf * 16 + (lane & 15);
            if (p < CC_NP) {
                const size_t ob = ((size_t)b * CC_COUT + crow) * CC_NP + p;
#pragma unroll
                for (int j = 0; j < 4; ++j) out[ob + (size_t)j * CC_NP] = acc[mf][nf][j];
            }
        }
    }
}

// ---------------------------------------------------------------- launch ----
extern "C" void kernel_launch(void* const* d_in, const int* in_sizes, int n_in,
                              void* d_out, int out_size, void* d_ws, size_t ws_size,
                              hipStream_t stream) {
    const float* x   = (const float*)d_in[0];
    const float* ew  = (const float*)d_in[1];
    const float* rww = (const float*)d_in[2];
    const float* rwb = (const float*)d_in[3];
    float* out = (float*)d_out;
    char* ws = (char*)d_ws;

    __hip_bfloat16* xnhwc = (__hip_bfloat16*)ws;                    // 33,554,432 B
    __hip_bfloat16* cwcmb = (__hip_bfloat16*)(ws + 33554432);       // 18,874,368 B
    float* psum   = (float*)(ws + 52428800);                        //  1,048,576 B
    float* pooled = (float*)(ws + 53477376);                        //     16,384 B
    float* rwts   = (float*)(ws + 53493760);                        //      1,024 B

    cc_nhwc<<<dim3(CC_B * 64), dim3(256), 0, stream>>>(x, xnhwc, psum);
    cc_reduce<<<dim3(CC_B), dim3(128), 0, stream>>>(psum, pooled);
    cc_routing<<<dim3(1), dim3(256), 0, stream>>>(pooled, rww, rwb, rwts);
    cc_combine<<<dim3(9 * CC_COUT), dim3(128), 0, stream>>>(ew, rwts, cwcmb);
    cc_conv<<<dim3(16, CC_B), dim3(512), 0, stream>>>(xnhwc, cwcmb, out);
}

// Round 4
// 127.152 us; speedup vs baseline: 1.0576x; 1.0576x over previous
//
#include <hip/hip_runtime.h>
#include <hip/hip_bf16.h>

// CondConv: B=32, CIN=128, COUT=256, K=3, E=8, H=W=64 -> out [32,256,62,62] fp32
// Pipeline: nhwc(+pool partials) -> reduce -> routing -> combine(bf16 cw) ->
//           implicit-GEMM MFMA conv (128x128 tile, 4 waves, 64KB LDS ->
//           2 blocks/CU co-residency, counted vmcnt, XCD-locality decode).

#define CC_B    32
#define CC_CIN  128
#define CC_COUT 256
#define CC_NP   3844   // 62*62
#define CC_NT   18     // K-tiles: 9 taps x 2 cin-halves of 64

typedef __attribute__((ext_vector_type(8))) short bf16x8;
typedef __attribute__((ext_vector_type(4))) float f32x4;

// ------------------------------------------------- NHWC cast + pool partials
__global__ void cc_nhwc(const float* __restrict__ x, __hip_bfloat16* __restrict__ xn,
                        float* __restrict__ psum) {
    const int b = blockIdx.x >> 6, y = blockIdx.x & 63;   // 2048 blocks
    __shared__ float lds[64 * 129];                        // [x][cin], +1 pad
    __shared__ float sred[256];
    const int t = threadIdx.x;                             // 256
    const float* src = x + (size_t)b * CC_CIN * 4096 + y * 64;
#pragma unroll
    for (int i = 0; i < 32; ++i) {
        const int idx = i * 256 + t;
        const int cin = idx >> 6, xx = idx & 63;
        lds[xx * 129 + cin] = src[(size_t)cin * 4096 + xx];
    }
    __syncthreads();
    __hip_bfloat16* dst = xn + ((size_t)b * 4096 + y * 64) * CC_CIN;
#pragma unroll
    for (int j = 0; j < 4; ++j) {
        const int cidx = j * 256 + t;                      // 1024 chunks of 8 cin
        const int xx = cidx >> 4, c8 = (cidx & 15) * 8;
        union { __hip_bfloat16 h[8]; uint4 v; } u;
#pragma unroll
        for (int jj = 0; jj < 8; ++jj) u.h[jj] = __float2bfloat16(lds[xx * 129 + c8 + jj]);
        *reinterpret_cast<uint4*>(dst + (size_t)xx * CC_CIN + c8) = u.v;
    }
    // pool partial: sum over the 64 x's of this row
    const int cin = t & 127, xh = (t >> 7) * 32;
    float s = 0.f;
#pragma unroll
    for (int xx = 0; xx < 32; ++xx) s += lds[(xh + xx) * 129 + cin];
    sred[t] = s;
    __syncthreads();
    if (t < 128) psum[((size_t)b * 64 + y) * CC_CIN + t] = sred[t] + sred[t + 128];
}

// ----------------------------------------------------------------- reduce --
__global__ void cc_reduce(const float* __restrict__ psum, float* __restrict__ pooled) {
    const int b = blockIdx.x, c = threadIdx.x;             // 32 blocks x 128
    const float* p = psum + (size_t)b * 64 * CC_CIN + c;
    float s = 0.f;
#pragma unroll 8
    for (int y = 0; y < 64; ++y) s += p[(size_t)y * CC_CIN];
    pooled[b * CC_CIN + c] = s * (1.f / 4096.f);
}

// -------------------------------------------------------------- routing -----
__global__ void cc_routing(const float* __restrict__ pooled,
                           const float* __restrict__ rw_w,
                           const float* __restrict__ rw_b,
                           float* __restrict__ rweights) {
    const int t = threadIdx.x;                 // 256 = 32 b x 8 e
    const int b = t >> 3, e = t & 7;
    const float* p = pooled + b * CC_CIN;
    const float* w = rw_w + e * CC_CIN;
    float acc = rw_b[e];
#pragma unroll 8
    for (int i = 0; i < CC_CIN; ++i) acc += p[i] * w[i];
    float m = acc;
#pragma unroll
    for (int off = 1; off < 8; off <<= 1) m = fmaxf(m, __shfl_xor(m, off, 64));
    const float ex = __expf(acc - m);
    float sum = ex;
#pragma unroll
    for (int off = 1; off < 8; off <<= 1) sum += __shfl_xor(sum, off, 64);
    rweights[t] = ex / sum;
}

// -------------------------------------------------------------- combine -----
// cw[b][t9][cout][cin] (bf16) = sum_e rw[b][e] * EW[e][cout][cin][ky][kx]
__global__ void cc_combine(const float* __restrict__ ew,
                           const float* __restrict__ rw,
                           __hip_bfloat16* __restrict__ cw) {
    const int t9 = blockIdx.x >> 8;            // 0..8
    const int cout = blockIdx.x & 255;
    const int cin = threadIdx.x;               // 128 threads
    __shared__ float rws[256];
    rws[cin] = rw[cin];
    rws[cin + 128] = rw[cin + 128];
    __syncthreads();
    float wv[8];
    const size_t base = ((size_t)cout * CC_CIN + cin) * 9 + t9;
#pragma unroll
    for (int e = 0; e < 8; ++e) wv[e] = ew[base + (size_t)e * (CC_COUT * CC_CIN * 9)];
#pragma unroll 4
    for (int b = 0; b < CC_B; ++b) {
        float acc = 0.f;
#pragma unroll
        for (int e = 0; e < 8; ++e) acc += rws[b * 8 + e] * wv[e];
        cw[(((size_t)b * 9 + t9) * CC_COUT + cout) * CC_CIN + cin] = __float2bfloat16(acc);
    }
}

// ----------------------------------------------------------------- conv -----
__device__ __forceinline__ void gload_lds16(const void* g, void* l) {
    __builtin_amdgcn_global_load_lds(
        (const __attribute__((address_space(1))) unsigned int*)g,
        (__attribute__((address_space(3))) unsigned int*)l, 16, 0, 0);
}

// grid 1984 blocks, block 256 (4 waves, 2M x 2N). Tile BM=128 couts x BN=128
// pos, BK=64. LDS 64KB (A dbuf 2x16KB @0, B dbuf 2x16KB @32KB) -> 2 blocks/CU
// co-resident: per SIMD one wave of each block, independent barriers -> LDS
// phases of one block overlap MFMA phases of the other (m114).
// XCD-locality decode: XCD k (= blk&7) owns b in {4k..4k+3}; working set
// ~1.6MB per XCD fits its 4MB L2.
// Per K-tile: open vmcnt(8) [stage(t) retired, stage(t+1) in flight] +
// barrier; free-flow ds_read+MFMA (compiler-scheduled lgkmcnt); close
// lgkmcnt(0)+barrier; stage(t+2). Swizzle: slot s of 128B row r holds source
// chunk s^(r&7) (linear global_load_lds dest, pre-swizzled per-lane source).
__global__ __launch_bounds__(256, 2) void cc_conv(
    const __hip_bfloat16* __restrict__ xn,   // [B][64][64][128]
    const __hip_bfloat16* __restrict__ cw,   // [B][9][256][128]
    float* __restrict__ out)                 // [B][256][3844]
{
    __shared__ __align__(16) char smem[65536];
    // ---- XCD-aware block decode (bijective over 1984 = 8 xcd x 4 b x 62)
    const int l   = blockIdx.x;
    const int xcd = l & 7, li = l >> 3;          // li in [0,248)
    const int b   = 4 * xcd + li / 62;
    const int r2  = li % 62;
    const int m0  = (r2 & 1) * 128;
    const int n0  = (r2 >> 1) * 128;

    const int tid = threadIdx.x;
    const int wid = tid >> 6, lane = tid & 63;   // wid 0..3
    const int waveM = wid >> 1, waveN = wid & 1;

    f32x4 acc[4][4];
#pragma unroll
    for (int i = 0; i < 4; ++i)
#pragma unroll
        for (int j = 0; j < 4; ++j) acc[i][j] = (f32x4){0.f, 0.f, 0.f, 0.f};

    // staging: wave w, issue i covers rows w*32+i*8..+7; lane -> row l>>3,
    // slot l&7; source chunk pre-swizzled: slot s of row r gets chunk s^(r&7)
    const int gsw = (lane & 7) ^ (lane >> 3);
    int laOff[4], lbOff[4];
#pragma unroll
    for (int i = 0; i < 4; ++i) {
        const int row = wid * 32 + i * 8 + (lane >> 3);   // 0..127
        laOff[i] = (m0 + row) * CC_CIN + gsw * 8;
        int p = n0 + row; if (p > CC_NP - 1) p = CC_NP - 1;   // tail clamp
        const int oy = p / 62, ox = p - oy * 62;
        lbOff[i] = (oy * 64 + ox) * CC_CIN + gsw * 8;
    }

    const __hip_bfloat16* cwb = cw + (size_t)b * 9 * CC_COUT * CC_CIN;
    const __hip_bfloat16* xnb = xn + (size_t)b * 4096 * CC_CIN;

    auto stageK = [&](int t) {
        const int t9 = t >> 1;
        const int ky = (t9 * 11) >> 5;          // t9/3 for t9<9
        const int kx = t9 - ky * 3;
        const int aoff = t9 * (CC_COUT * CC_CIN) + (t & 1) * 64;
        const int boff = (ky * 64 + kx) * CC_CIN + (t & 1) * 64;
        char* Ab = smem + (t & 1) * 16384 + wid * 4096;
        char* Bb = smem + 32768 + (t & 1) * 16384 + wid * 4096;
#pragma unroll
        for (int i = 0; i < 4; ++i)
            gload_lds16(cwb + aoff + laOff[i], Ab + i * 1024);
#pragma unroll
        for (int i = 0; i < 4; ++i)
            gload_lds16(xnb + boff + lbOff[i], Bb + i * 1024);
    };

    const int rl = lane & 15, q = lane >> 4;

    // prologue: 2 K-tiles in flight (16 loads/wave)
    stageK(0);
    stageK(1);

#pragma unroll 1
    for (int t = 0; t < CC_NT; ++t) {
        const char* Ab = smem + (t & 1) * 16384;
        const char* Bb = smem + 32768 + (t & 1) * 16384;

        // ---- tile open: stage(t) globally visible
        if (t < CC_NT - 1) asm volatile("s_waitcnt vmcnt(8)" ::: "memory");
        else               asm volatile("s_waitcnt vmcnt(0)" ::: "memory");
        asm volatile("s_barrier" ::: "memory");

        // ---- free-flow reads + MFMA (compiler schedules counted lgkmcnt)
        bf16x8 af[8], bf[8];
#pragma unroll
        for (int mf = 0; mf < 4; ++mf)
#pragma unroll
            for (int kk = 0; kk < 2; ++kk) {
                const int r = waveM * 64 + mf * 16 + rl;
                af[mf * 2 + kk] = *(const bf16x8*)(Ab + r * 128 + (((kk * 4 + q) ^ (r & 7)) * 16));
            }
#pragma unroll
        for (int nf = 0; nf < 4; ++nf)
#pragma unroll
            for (int kk = 0; kk < 2; ++kk) {
                const int r = waveN * 64 + nf * 16 + rl;
                bf[nf * 2 + kk] = *(const bf16x8*)(Bb + r * 128 + (((kk * 4 + q) ^ (r & 7)) * 16));
            }
#pragma unroll
        for (int mf = 0; mf < 4; ++mf)
#pragma unroll
            for (int nf = 0; nf < 4; ++nf)
#pragma unroll
                for (int kk = 0; kk < 2; ++kk)
                    acc[mf][nf] = __builtin_amdgcn_mfma_f32_16x16x32_bf16(
                        af[mf * 2 + kk], bf[nf * 2 + kk], acc[mf][nf], 0, 0, 0);

        // ---- close: all reads of buf[t&1] done before stage(t+2) overwrites
        asm volatile("s_waitcnt lgkmcnt(0)" ::: "memory");
        asm volatile("s_barrier" ::: "memory");
        if (t + 2 < CC_NT) stageK(t + 2);
    }

    // epilogue: C/D map col=lane&15 (p), row=(lane>>4)*4+j (cout)
    const int q4 = (lane >> 4) * 4;
#pragma unroll
    for (int mf = 0; mf < 4; ++mf) {
        const int crow = m0 + waveM * 64 + mf * 16 + q4;
#pragma unroll
        for (int nf = 0; nf < 4; ++nf) {
            const int p = n0 + waveN * 64 + nf * 16 + (lane & 15);
            if (p < CC_NP) {
                const size_t ob = ((size_t)b * CC_COUT + crow) * CC_NP + p;
#pragma unroll
                for (int j = 0; j < 4; ++j) out[ob + (size_t)j * CC_NP] = acc[mf][nf][j];
            }
        }
    }
}

// ---------------------------------------------------------------- launch ----
extern "C" void kernel_launch(void* const* d_in, const int* in_sizes, int n_in,
                              void* d_out, int out_size, void* d_ws, size_t ws_size,
                              hipStream_t stream) {
    const float* x   = (const float*)d_in[0];
    const float* ew  = (const float*)d_in[1];
    const float* rww = (const float*)d_in[2];
    const float* rwb = (const float*)d_in[3];
    float* out = (float*)d_out;
    char* ws = (char*)d_ws;

    __hip_bfloat16* xnhwc = (__hip_bfloat16*)ws;                    // 33,554,432 B
    __hip_bfloat16* cwcmb = (__hip_bfloat16*)(ws + 33554432);       // 18,874,368 B
    float* psum   = (float*)(ws + 52428800);                        //  1,048,576 B
    float* pooled = (float*)(ws + 53477376);                        //     16,384 B
    float* rwts   = (float*)(ws + 53493760);                        //      1,024 B

    cc_nhwc<<<dim3(CC_B * 64), dim3(256), 0, stream>>>(x, xnhwc, psum);
    cc_reduce<<<dim3(CC_B), dim3(128), 0, stream>>>(psum, pooled);
    cc_routing<<<dim3(1), dim3(256), 0, stream>>>(pooled, rww, rwb, rwts);
    cc_combine<<<dim3(9 * CC_COUT), dim3(128), 0, stream>>>(ew, rwts, cwcmb);
    cc_conv<<<dim3(1984), dim3(256), 0, stream>>>(xnhwc, cwcmb, out);
}